// Round 9
// baseline (212.230 us; speedup 1.0000x reference)
//
#include <hip/hip_runtime.h>

#define BB 8
#define NN 4096
#define LL 4096
#define CC 256

typedef short bf16x8 __attribute__((ext_vector_type(8)));
typedef _Float16 f16x8 __attribute__((ext_vector_type(8)));
typedef __fp16 hf16x2 __attribute__((ext_vector_type(2)));  // cvt_pkrtz return type
typedef float f32x4 __attribute__((ext_vector_type(4)));

__device__ __forceinline__ short f2bf(float f) {
  union { float f; unsigned u; } v; v.f = f;
  unsigned r = v.u + 0x7fffu + ((v.u >> 16) & 1u);
  return (short)(r >> 16);
}
// 8 consecutive f32 -> bf16x8 MFMA fragment (two float4 loads)
__device__ __forceinline__ bf16x8 ld8(const float* __restrict__ fp) {
  float4 a = *(const float4*)fp;
  float4 b = *(const float4*)(fp + 4);
  bf16x8 r;
  r[0] = f2bf(a.x); r[1] = f2bf(a.y); r[2] = f2bf(a.z); r[3] = f2bf(a.w);
  r[4] = f2bf(b.x); r[5] = f2bf(b.y); r[6] = f2bf(b.z); r[7] = f2bf(b.w);
  return r;
}

// ---------------------------------------------------------------------------
// Kernel A: projections (f32 inputs).  Also zeroes Zbuf (used by kb1 atomics;
// stream order guarantees completion before kb1 starts).
// ---------------------------------------------------------------------------
__global__ __launch_bounds__(256) void ka_proj(
    const float* __restrict__ graph, const float* __restrict__ img,
    const float* __restrict__ Wq, const float* __restrict__ bq,
    const float* __restrict__ Wk, const float* __restrict__ bk,
    const float* __restrict__ Wv, const float* __restrict__ bv,
    short* __restrict__ Qb, short* __restrict__ Kt, _Float16* __restrict__ Vt,
    float* __restrict__ Zbuf)
{
  const int tid = threadIdx.x;
  const int w = tid >> 6, lane = tid & 63, lo = lane & 15, q = lane >> 4;
  const int bid = blockIdx.x;
  if (bid < 512) {
    const int b = bid >> 6;
    if (tid < 64) Zbuf[(size_t)b * LL + ((bid & 63) << 6) + tid] = 0.0f;
    const int lt = ((bid & 63) << 6) + (w << 4);
    f32x4 aK0 = {0,0,0,0}, aK1 = {0,0,0,0}, aV0 = {0,0,0,0}, aV1 = {0,0,0,0};
    const float* ib = img + (size_t)b * CC * LL + lt + lo;
    #pragma unroll
    for (int cs = 0; cs < 8; ++cs) {
      const int c0 = cs * 32 + q * 8;
      bf16x8 bi;
      #pragma unroll
      for (int j = 0; j < 8; ++j) bi[j] = f2bf(ib[(size_t)(c0 + j) * LL]);
      bf16x8 wk0 = ld8(Wk + lo * CC + c0);
      bf16x8 wk1 = ld8(Wk + (lo + 16) * CC + c0);
      bf16x8 wv0 = ld8(Wv + lo * CC + c0);
      bf16x8 wv1 = ld8(Wv + (lo + 16) * CC + c0);
      aK0 = __builtin_amdgcn_mfma_f32_16x16x32_bf16(wk0, bi, aK0, 0, 0, 0);
      aK1 = __builtin_amdgcn_mfma_f32_16x16x32_bf16(wk1, bi, aK1, 0, 0, 0);
      aV0 = __builtin_amdgcn_mfma_f32_16x16x32_bf16(wv0, bi, aV0, 0, 0, 0);
      aV1 = __builtin_amdgcn_mfma_f32_16x16x32_bf16(wv1, bi, aV1, 0, 0, 0);
    }
    const float kscale = 0.2550348663f;  // log2(e)/sqrt(32)
    const size_t row = ((size_t)b * LL + lt + lo) * 32;
    short4 s0, s1;
    s0.x = f2bf((aK0[0] + bk[q * 4 + 0]) * kscale);
    s0.y = f2bf((aK0[1] + bk[q * 4 + 1]) * kscale);
    s0.z = f2bf((aK0[2] + bk[q * 4 + 2]) * kscale);
    s0.w = f2bf((aK0[3] + bk[q * 4 + 3]) * kscale);
    s1.x = f2bf((aK1[0] + bk[16 + q * 4 + 0]) * kscale);
    s1.y = f2bf((aK1[1] + bk[16 + q * 4 + 1]) * kscale);
    s1.z = f2bf((aK1[2] + bk[16 + q * 4 + 2]) * kscale);
    s1.w = f2bf((aK1[3] + bk[16 + q * 4 + 3]) * kscale);
    *(short4*)(Kt + row + q * 4) = s0;
    *(short4*)(Kt + row + 16 + q * 4) = s1;
    union { hf16x2 h[2]; uint2 u; } p0, p1;
    p0.h[0] = __builtin_amdgcn_cvt_pkrtz(aV0[0] + bv[q * 4 + 0], aV0[1] + bv[q * 4 + 1]);
    p0.h[1] = __builtin_amdgcn_cvt_pkrtz(aV0[2] + bv[q * 4 + 2], aV0[3] + bv[q * 4 + 3]);
    p1.h[0] = __builtin_amdgcn_cvt_pkrtz(aV1[0] + bv[16 + q * 4 + 0], aV1[1] + bv[16 + q * 4 + 1]);
    p1.h[1] = __builtin_amdgcn_cvt_pkrtz(aV1[2] + bv[16 + q * 4 + 2], aV1[3] + bv[16 + q * 4 + 3]);
    *(uint2*)(Vt + row + q * 4) = p0.u;
    *(uint2*)(Vt + row + 16 + q * 4) = p1.u;
  } else {
    const int t = bid - 512;
    const int b = t >> 6;
    const int nt = ((t & 63) << 6) + (w << 4);
    bf16x8 ag = ld8(graph + ((size_t)b * NN + nt + lo) * 32 + q * 8);
    bf16x8 w0 = ld8(Wq + lo * 32 + q * 8);
    bf16x8 w1 = ld8(Wq + (lo + 16) * 32 + q * 8);
    f32x4 z = {0,0,0,0};
    f32x4 a0 = __builtin_amdgcn_mfma_f32_16x16x32_bf16(ag, w0, z, 0, 0, 0);
    f32x4 a1 = __builtin_amdgcn_mfma_f32_16x16x32_bf16(ag, w1, z, 0, 0, 0);
    const float b0 = bq[lo], b1 = bq[lo + 16];
    #pragma unroll
    for (int r = 0; r < 4; ++r) {
      const size_t rowq = ((size_t)b * NN + nt + q * 4 + r) * 32;
      Qb[rowq + lo] = f2bf(a0[r] + b0);
      Qb[rowq + 16 + lo] = f2bf(a1[r] + b1);
    }
  }
}

// ---------------------------------------------------------------------------
// Kernel B1: partial softmax denominators (unchanged from r7, XCD-pinned).
// ---------------------------------------------------------------------------
__global__ __launch_bounds__(256) void kb1_z(
    const short* __restrict__ Qb, const short* __restrict__ Kt,
    float* __restrict__ Z)
{
  const int tid = threadIdx.x;
  const int w = tid >> 6, lane = tid & 63, lo = lane & 15, q = lane >> 4;
  const int bid = blockIdx.x;
  const int b = bid & 7;           // XCD-partition: one b per XCD
  const int t = bid >> 3;          // 0..255 within the XCD
  const int l0 = (t & 63) << 6;
  const int nq = t >> 6;           // 0..3
  bf16x8 kf[4];
  #pragma unroll
  for (int f = 0; f < 4; ++f)
    kf[f] = *(const bf16x8*)(Kt + ((size_t)b * LL + l0 + f * 16 + lo) * 32 + q * 8);
  float za[4][4] = {{0}};
  const short* qbase = Qb + ((size_t)b * NN + nq * 1024 + w * 256 + lo) * 32 + q * 8;
  #pragma unroll 4
  for (int it = 0; it < 16; ++it) {
    bf16x8 qf = *(const bf16x8*)(qbase + it * 512);
    #pragma unroll
    for (int f = 0; f < 4; ++f) {
      f32x4 z = {0,0,0,0};
      f32x4 c = __builtin_amdgcn_mfma_f32_16x16x32_bf16(kf[f], qf, z, 0, 0, 0);
      #pragma unroll
      for (int r = 0; r < 4; ++r) za[f][r] += __builtin_amdgcn_exp2f(c[r]);
    }
  }
  #pragma unroll
  for (int m = 1; m < 16; m <<= 1)
    #pragma unroll
    for (int f = 0; f < 4; ++f)
      #pragma unroll
      for (int r = 0; r < 4; ++r)
        za[f][r] += __shfl_xor(za[f][r], m, 64);
  if (lo == 0) {
    #pragma unroll
    for (int f = 0; f < 4; ++f)
      #pragma unroll
      for (int r = 0; r < 4; ++r)
        atomicAdd(&Z[(size_t)b * LL + l0 + f * 16 + q * 4 + r], za[f][r]);
  }
}

// ---------------------------------------------------------------------------
// Kernel B2: Vpp[b][o][l] = Vt[b][l][o] * (4096 / Z_l)  (f16, [o][l] layout).
// ---------------------------------------------------------------------------
__global__ __launch_bounds__(256) void kb2_scale(
    const _Float16* __restrict__ Vt, const float* __restrict__ Z,
    _Float16* __restrict__ Vpp)
{
  const int tid = threadIdx.x;
  const int b = blockIdx.x >> 6;
  const int l = ((blockIdx.x & 63) << 6) + (tid & 63);
  const int og = tid >> 6;  // 0..3
  const float inv = __builtin_amdgcn_rcpf(Z[(size_t)b * LL + l]) * 4096.0f;
  const f16x8 vv = *(const f16x8*)(Vt + ((size_t)b * LL + l) * 32 + og * 8);
  #pragma unroll
  for (int j = 0; j < 8; ++j)
    Vpp[((size_t)b * 32 + og * 8 + j) * LL + l] = (_Float16)((float)vv[j] * inv);
}

// ---------------------------------------------------------------------------
// Kernel C v2: block-level K/V reuse.  r1-r7 showed kc pinned at 57.5us
// invariant to pipelining/exp2-pipe/cache-level: the invariant is per-CU
// cache-LINE requests (32K lines = 2MB at ~16B/cy L1 streaming = 54.6us).
// Fix: grid 256 (1 block/CU, b=bid&7 XCD-pinned), 512 thr / 8 waves; block
// covers 128 n; all 8 waves lockstep over 64 lc-tiles; K/V staged once per
// tile into double-buffered LDS by all threads -> per-CU global traffic
// 512KB (4x less).  V consumed lag-1 from registers (avoids dbuf clobber);
// per-wave P ping-pong; reads-before-writes body order (in-order LDS queue);
// one barrier per body.  Per-wave msg is complete -> no cross-wave epilogue
// reduction.  LDS 56.3KB; plain launch_bounds(512) (block shape caps VGPR
// at 256 -- r2 lesson: never cap below need).
// ---------------------------------------------------------------------------
#define KC2_BODY(LC, PW, PR, KC_, VC_, KN_, VN_, DOPV)                        \
  {                                                                           \
    const int lcn_ = ((LC) + 1 < 64) ? (LC) + 1 : (LC);                       \
    uint2 kx_ = *(const uint2*)(kgsrc + (size_t)lcn_ * 2048);                 \
    uint2 vx_ = *(const uint2*)(vgsrc + (size_t)lcn_ * 64);                   \
    bf16x8 kf_[4];                                                            \
    _Pragma("unroll")                                                         \
    for (int f = 0; f < 4; ++f)                                               \
      kf_[f] = *(const bf16x8*)((KC_) + (f * 16 + lo) * 40 + q * 8);          \
    f16x8 nA0_ = *(const f16x8*)((VC_) + lo * 72 + q * 8);                    \
    f16x8 nA1_ = *(const f16x8*)((VC_) + lo * 72 + 32 + q * 8);               \
    f16x8 nB0_ = *(const f16x8*)((VC_) + (16 + lo) * 72 + q * 8);             \
    f16x8 nB1_ = *(const f16x8*)((VC_) + (16 + lo) * 72 + 32 + q * 8);        \
    if (DOPV) {                                                               \
      f16x8 pa0_ = *(const f16x8*)((PR) + lo * 72 + q * 8);                   \
      f16x8 pa1_ = *(const f16x8*)((PR) + lo * 72 + 32 + q * 8);              \
      m00 = __builtin_amdgcn_mfma_f32_16x16x32_f16(pa0_, vA0, m00, 0, 0, 0);  \
      m01 = __builtin_amdgcn_mfma_f32_16x16x32_f16(pa0_, vB0, m01, 0, 0, 0);  \
      m00 = __builtin_amdgcn_mfma_f32_16x16x32_f16(pa1_, vA1, m00, 0, 0, 0);  \
      m01 = __builtin_amdgcn_mfma_f32_16x16x32_f16(pa1_, vB1, m01, 0, 0, 0);  \
    }                                                                         \
    _Pragma("unroll")                                                         \
    for (int f = 0; f < 4; ++f) {                                             \
      f32x4 z_ = {0, 0, 0, 0};                                                \
      f32x4 c_ = __builtin_amdgcn_mfma_f32_16x16x32_bf16(kf_[f], qf, z_, 0, 0, 0); \
      union { hf16x2 h[2]; uint2 u; } pk_;                                    \
      pk_.h[0] = __builtin_amdgcn_cvt_pkrtz(__builtin_amdgcn_exp2f(c_[0]),    \
                                            __builtin_amdgcn_exp2f(c_[1]));   \
      pk_.h[1] = __builtin_amdgcn_cvt_pkrtz(__builtin_amdgcn_exp2f(c_[2]),    \
                                            __builtin_amdgcn_exp2f(c_[3]));   \
      *(uint2*)&(PW)[lo * 72 + f * 16 + q * 4] = pk_.u;                       \
    }                                                                         \
    *(uint2*)((KN_) + kl * 40 + kc8 * 4) = kx_;                               \
    *(uint2*)((VN_) + vo * 72 + vc16 * 4) = vx_;                              \
    __syncthreads();                                                          \
    vA0 = nA0_; vA1 = nA1_; vB0 = nB0_; vB1 = nB1_;                           \
  }

__global__ __launch_bounds__(512) void kc_attn(
    const short* __restrict__ Qb, const short* __restrict__ Kt,
    const _Float16* __restrict__ Vpp, const float* __restrict__ graph,
    const float* __restrict__ Wc, const float* __restrict__ bc,
    float* __restrict__ out)
{
  // LDS: [P: 8w x 2buf x 16x72 halfs = 36864][K: 2 x 64x40 shorts = 10240]
  //      [V: 2 x 32x72 halfs = 9216]  -> 56320 B
  __shared__ __align__(16) unsigned char smem[56320];
  const int tid = threadIdx.x;
  const int w = tid >> 6, lane = tid & 63, lo = lane & 15, q = lane >> 4;
  const int b = blockIdx.x & 7;              // XCD-pinned: one b per XCD
  const int n0 = ((int)blockIdx.x >> 3) << 7;  // 32 tiles of 128 n
  _Float16* PA = (_Float16*)smem + w * 2304;           // [16][72]
  _Float16* PB = PA + 1152;
  short* KT0 = (short*)(smem + 36864);                 // [64][40]
  short* KT1 = KT0 + 2560;
  _Float16* VT0 = (_Float16*)(smem + 47104);           // [32][72]
  _Float16* VT1 = VT0 + 2304;
  // Q: wave w owns rows n0 + w*16 .. +15
  const bf16x8 qf = *(const bf16x8*)(Qb + ((size_t)b * NN + n0 + w * 16 + lo) * 32 + q * 8);
  f32x4 m00 = {0,0,0,0}, m01 = {0,0,0,0};
  // staging sources (per thread)
  const int kl = tid >> 3, kc8 = tid & 7;    // K: row l (0..63), 8B chunk
  const short* kgsrc = Kt + (size_t)b * LL * 32 + kl * 32 + kc8 * 4;
  const int vo = tid >> 4, vc16 = tid & 15;  // V: row o (0..31), 8B chunk
  const _Float16* vgsrc = Vpp + ((size_t)b * 32 + vo) * LL + vc16 * 4;
  // prologue: stage tile 0 -> buf0
  {
    uint2 kx = *(const uint2*)(kgsrc);
    uint2 vx = *(const uint2*)(vgsrc);
    *(uint2*)(KT0 + kl * 40 + kc8 * 4) = kx;
    *(uint2*)(VT0 + vo * 72 + vc16 * 4) = vx;
    __syncthreads();
  }
  f16x8 vA0 = {0,0,0,0,0,0,0,0}, vA1 = {0,0,0,0,0,0,0,0};
  f16x8 vB0 = {0,0,0,0,0,0,0,0}, vB1 = {0,0,0,0,0,0,0,0};
  #pragma unroll 1
  for (int i2 = 0; i2 < 32; ++i2) {
    const int lce = i2 * 2;
    KC2_BODY(lce,     PA, PB, KT0, VT0, KT1, VT1, (i2 != 0));
    KC2_BODY(lce + 1, PB, PA, KT1, VT1, KT0, VT0, true);
  }
  // drain: PV of P(63) (in PB) with V(63) (in vA/vB regs)
  {
    f16x8 pa0 = *(const f16x8*)(PB + lo * 72 + q * 8);
    f16x8 pa1 = *(const f16x8*)(PB + lo * 72 + 32 + q * 8);
    m00 = __builtin_amdgcn_mfma_f32_16x16x32_f16(pa0, vA0, m00, 0, 0, 0);
    m01 = __builtin_amdgcn_mfma_f32_16x16x32_f16(pa0, vB0, m01, 0, 0, 0);
    m00 = __builtin_amdgcn_mfma_f32_16x16x32_f16(pa1, vA1, m00, 0, 0, 0);
    m01 = __builtin_amdgcn_mfma_f32_16x16x32_f16(pa1, vB1, m01, 0, 0, 0);
  }
  // per-wave msg is complete (full l range): bounce through own P region
  // ([16 n][36] f32 = 2304B < 4608B own region), no cross-wave reduction.
  float* MSw = (float*)((unsigned char*)smem + w * 4608);
  #pragma unroll
  for (int r = 0; r < 4; ++r) {
    MSw[(q * 4 + r) * 36 + lo] = m00[r];
    MSw[(q * 4 + r) * 36 + 16 + lo] = m01[r];
  }
  // epilogue: out[n][o] = graph + bc[o] + sum_c Wc[o][c]*msg[n][c] / 4096
  const int o = lane & 31, nh = lane >> 5;
  const float bcv = bc[o];
  #pragma unroll
  for (int rr = 0; rr < 8; ++rr) {
    const int nl = nh * 8 + rr;  // 0..15 within wave
    f32x4 s = {0,0,0,0};
    #pragma unroll
    for (int cc = 0; cc < 8; ++cc) {
      f32x4 m4 = *(const f32x4*)&MSw[nl * 36 + cc * 4];
      float4 wc4 = *(const float4*)(Wc + o * 32 + cc * 4);
      s[0] += wc4.x * m4[0];
      s[1] += wc4.y * m4[1];
      s[2] += wc4.z * m4[2];
      s[3] += wc4.w * m4[3];
    }
    const size_t idx = ((size_t)b * NN + n0 + w * 16 + nl) * 32 + o;
    out[idx] = (s[0] + s[1] + s[2] + s[3]) * (1.0f / 4096.0f) + bcv + graph[idx];
  }
}

// ---------------------------------------------------------------------------
extern "C" void kernel_launch(void* const* d_in, const int* in_sizes, int n_in,
                              void* d_out, int out_size, void* d_ws, size_t ws_size,
                              hipStream_t stream) {
  const float* graph = (const float*)d_in[0];
  const float* img   = (const float*)d_in[1];
  const float* Wq    = (const float*)d_in[2];
  const float* bq    = (const float*)d_in[3];
  const float* Wk    = (const float*)d_in[4];
  const float* bk    = (const float*)d_in[5];
  const float* Wv    = (const float*)d_in[6];
  const float* bv    = (const float*)d_in[7];
  const float* Wc    = (const float*)d_in[8];
  const float* bc    = (const float*)d_in[9];
  char* ws = (char*)d_ws;
  short*    Qb  = (short*)(ws + 0);          // 2 MB   bf16 [B][N][32]
  short*    Kt  = (short*)(ws + 2097152);    // 2 MB   bf16 [B][L][32] (scaled)
  _Float16* Vt  = (_Float16*)(ws + 4194304); // 2 MB   f16  [B][L][32]
  _Float16* Vpp = (_Float16*)(ws + 6291456); // 2 MB   f16  [B][32][L] (V*4096/Z)
  float*    Zb  = (float*)(ws + 8388608);    // 128 KB f32  [B][L]
  ka_proj<<<dim3(1024), dim3(256), 0, stream>>>(graph, img, Wq, bq, Wk, bk, Wv, bv,
                                                Qb, Kt, Vt, Zb);
  kb1_z<<<dim3(2048), dim3(256), 0, stream>>>(Qb, Kt, Zb);
  kb2_scale<<<dim3(512), dim3(256), 0, stream>>>(Vt, Zb, Vpp);
  kc_attn<<<dim3(256), dim3(512), 0, stream>>>(Qb, Kt, Vpp, graph, Wc, bc,
                                               (float*)d_out);
}